// Round 1
// 312.515 us; speedup vs baseline: 1.0426x; 1.0426x over previous
//
#include <hip/hip_runtime.h>
#include <stdint.h>

#define S_ROWS 100000
#define NQ     2048
#define M_POS  16
#define VOCABS 32
#define WPB    8      // 32-query words per score block (256 queries)
#define GROUPS 8      // 2048 / 256
#define CHUNKS 125
#define RC     800    // rows per chunk
#define KITER  25     // RC / 32
#define KPAD   264    // padded stride for keys transpose (conflict-free)

// ---------------- kernel 1: decode one-hot support rows to token bytes (v*8) ----
// Also zero-inits best[] (workspace is re-poisoned each iteration, and poison
// garbage would beat any real key in the atomicMax).
__global__ __launch_bounds__(256) void knn_decode(const float* __restrict__ support,
                                                  uint8_t* __restrict__ tok,
                                                  uint32_t* __restrict__ best) {
    if (blockIdx.x < 8) best[blockIdx.x * 256 + threadIdx.x] = 0u;
    int wave = (blockIdx.x * 256 + threadIdx.x) >> 6;   // one wave per row
    int lane = threadIdx.x & 63;
    if (wave >= S_ROWS) return;
    const float4* rowp = (const float4*)(support + (size_t)wave * 512) + lane * 2;
    float4 f0 = rowp[0];
    float4 f1 = rowp[1];
    // token index within position = (lane&3)*8 + i ; store pre-scaled by 8 (fits u8: <=248)
    float base = (float)((lane & 3) * 64);
    float v = f0.x * (base + 0.f)  + f0.y * (base + 8.f)  + f0.z * (base + 16.f) + f0.w * (base + 24.f)
            + f1.x * (base + 32.f) + f1.y * (base + 40.f) + f1.z * (base + 48.f) + f1.w * (base + 56.f);
    v += __shfl_xor(v, 1);
    v += __shfl_xor(v, 2);
    if ((lane & 3) == 0) {
        int p = lane >> 2;
        tok[(size_t)wave * 16 + p] = (uint8_t)(v + 0.5f);
    }
}

// full adder / half adder on bit-planes
__device__ __forceinline__ void FA(uint32_t a, uint32_t b, uint32_t c,
                                   uint32_t& s, uint32_t& co) {
    uint32_t x = a ^ b;
    s  = x ^ c;
    co = (a & b) | (x & c);
}
__device__ __forceinline__ void HA(uint32_t a, uint32_t b, uint32_t& s, uint32_t& co) {
    s = a ^ b; co = a & b;
}

// ---------------- kernel 2: bit-sliced match-count + argmax --------------------
// LDS: table (16 KB, live during main loop) aliased with keys transpose buffer
// (33.8 KB, live after) -> 34 KB total -> 4 blocks/CU.
// K-loop: PARTIAL unroll (5). Full 25x unroll hoisted up to 25 uint4 loads
// against the 128-VGPR launch_bounds clamp -> pressure/spill risk in the hot
// loop. The winning-iteration planes now use wave-uniform SALU masks instead
// of literal-k ternaries, so partial unroll costs no extra VALU.
__global__ __launch_bounds__(256, 4) void knn_score(const int* __restrict__ utts,
                                                    const uint8_t* __restrict__ tok,
                                                    uint32_t* __restrict__ best) {
    __shared__ uint32_t smem[32 * KPAD];               // 33.8 KB
    uint32_t* table = smem;                            // first 4096 words during main loop
    uint32_t* keys  = smem;                            // whole buffer, after main loop

    const int bid = blockIdx.x;
    const int g   = bid & 7;          // query group (256 queries)
    const int c   = bid >> 3;         // row chunk
    const int t   = threadIdx.x;

    // zero table
    #pragma unroll
    for (int i = 0; i < 16; ++i) table[t + 256 * i] = 0u;
    __syncthreads();

    // build query-bitmask table: B[m][v][w] bit j = (utts[m][g*256+w*32+j] == v)
    {
        int q = g * 256 + t;
        int wb = t >> 5, j = t & 31;
        #pragma unroll
        for (int m = 0; m < M_POS; ++m) {
            int v = utts[m * NQ + q];
            atomicOr(&table[(m * VOCABS + v) * WPB + wb], 1u << j);
        }
    }
    __syncthreads();

    const int w   = t & 7;            // which 32-query word this thread scores
    const int sub = t >> 3;           // row sub-lane (0..31)
    const int r0  = c * RC;
    const uint32_t* tw = table + w;

    uint32_t cp0=0,cp1=0,cp2=0,cp3=0,cp4=0;   // current-max count planes
    uint32_t k0p=0,k1p=0,k2p=0,k3p=0,k4p=0;   // winning-iteration planes

    const uint4* tbase = (const uint4*)(tok + (size_t)(r0 + sub) * 16);

    #pragma unroll 5
    for (int k = 0; k < KITER; ++k) {
        uint4 ta = tbase[32 * k];             // row s = r0 + sub + 32*k
        uint32_t b[16];
        b[0]  = tw[ (ta.x        & 0xFFu) +  0*256];
        b[1]  = tw[((ta.x >> 8)  & 0xFFu) +  1*256];
        b[2]  = tw[((ta.x >> 16) & 0xFFu) +  2*256];
        b[3]  = tw[((ta.x >> 24)        ) +  3*256];
        b[4]  = tw[ (ta.y        & 0xFFu) +  4*256];
        b[5]  = tw[((ta.y >> 8)  & 0xFFu) +  5*256];
        b[6]  = tw[((ta.y >> 16) & 0xFFu) +  6*256];
        b[7]  = tw[((ta.y >> 24)        ) +  7*256];
        b[8]  = tw[ (ta.z        & 0xFFu) +  8*256];
        b[9]  = tw[((ta.z >> 8)  & 0xFFu) +  9*256];
        b[10] = tw[((ta.z >> 16) & 0xFFu) + 10*256];
        b[11] = tw[((ta.z >> 24)        ) + 11*256];
        b[12] = tw[ (ta.w        & 0xFFu) + 12*256];
        b[13] = tw[((ta.w >> 8)  & 0xFFu) + 13*256];
        b[14] = tw[((ta.w >> 16) & 0xFFu) + 14*256];
        b[15] = tw[((ta.w >> 24)        ) + 15*256];

        // CSA tree: 16 one-bit planes -> 5-bit count planes n0..n4
        uint32_t s10,s11,s12,s13,s14, c10,c11,c12,c13,c14;
        FA(b[0],b[1],b[2],   s10,c10);
        FA(b[3],b[4],b[5],   s11,c11);
        FA(b[6],b[7],b[8],   s12,c12);
        FA(b[9],b[10],b[11], s13,c13);
        FA(b[12],b[13],b[14],s14,c14);
        uint32_t s2a,c2a,s2b,c2b;
        FA(s10,s11,s12, s2a,c2a);
        FA(s13,s14,b[15], s2b,c2b);
        uint32_t n0,h0;  HA(s2a,s2b, n0,h0);
        uint32_t u,cu,vv,cv,x2,cx,n1,cy;
        FA(c10,c11,c12, u,cu);
        FA(c13,c14,c2a, vv,cv);
        FA(u,vv,c2b,    x2,cx);
        HA(x2,h0,       n1,cy);
        uint32_t y4,cz,n2,cw,n3,n4;
        FA(cu,cv,cx, y4,cz);
        HA(y4,cy,    n2,cw);
        HA(cz,cw,    n3,n4);

        // gt = (new count > current max), 5-bit unsigned, bit-sliced
        uint32_t eq = ~(n4 ^ cp4);
        uint32_t gt = n4 & ~cp4;
        gt |= eq & (n3 & ~cp3);  eq &= ~(n3 ^ cp3);
        gt |= eq & (n2 & ~cp2);  eq &= ~(n2 ^ cp2);
        gt |= eq & (n1 & ~cp1);  eq &= ~(n1 ^ cp1);
        gt |= eq & (n0 & ~cp0);

        uint32_t ng = ~gt;
        cp0 = (gt & n0) | (ng & cp0);
        cp1 = (gt & n1) | (ng & cp1);
        cp2 = (gt & n2) | (ng & cp2);
        cp3 = (gt & n3) | (ng & cp3);
        cp4 = (gt & n4) | (ng & cp4);
        // wave-uniform masks of k's bits: SALU-computed, SGPR operand in the
        // VALU and/or below -> same cost as the literal-k version, but k no
        // longer needs to be a compile-time constant (enables partial unroll).
        uint32_t kb0 = 0u - (uint32_t)( k        & 1);
        uint32_t kb1 = 0u - (uint32_t)((k >> 1)  & 1);
        uint32_t kb2 = 0u - (uint32_t)((k >> 2)  & 1);
        uint32_t kb3 = 0u - (uint32_t)((k >> 3)  & 1);
        uint32_t kb4 = 0u - (uint32_t)((k >> 4)  & 1);
        k0p = (k0p & ng) | (gt & kb0);
        k1p = (k1p & ng) | (gt & kb1);
        k2p = (k2p & ng) | (gt & kb2);
        k3p = (k3p & ng) | (gt & kb3);
        k4p = (k4p & ng) | (gt & kb4);
    }

    __syncthreads();   // all table gathers done before keys overwrite the union

    // extract per-query packed keys into LDS (conflict-free layout, no atomics)
    // key = (cnt << 17) | (0x1FFFF - idx); idx = r0 + sub + 32*kk
    {
        uint32_t C = 0x1FFFFu - (uint32_t)(r0 + sub);
        #pragma unroll
        for (int j = 0; j < 32; ++j) {
            uint32_t cnt = ((cp0>>j)&1u) | (((cp1>>j)&1u)<<1) | (((cp2>>j)&1u)<<2)
                         | (((cp3>>j)&1u)<<3) | (((cp4>>j)&1u)<<4);
            uint32_t kk  = ((k0p>>j)&1u) | (((k1p>>j)&1u)<<1) | (((k2p>>j)&1u)<<2)
                         | (((k3p>>j)&1u)<<3) | (((k4p>>j)&1u)<<4);
            uint32_t key = (cnt << 17) + C - (kk << 5);
            keys[j * KPAD + t] = key;           // bank = t&31: conflict-free
        }
    }
    __syncthreads();

    // reduce: thread t owns query (w2 = t&7, j2 = t>>3); max over 32 sub-threads,
    // then one device-scope atomicMax per (query, block) -> 125 ops/address total.
    {
        int w2 = t & 7, j2 = t >> 3;
        const uint32_t* kp = keys + j2 * KPAD + w2;
        uint32_t bestv = 0;
        #pragma unroll
        for (int i = 0; i < 32; ++i) {
            uint32_t v = kp[8 * i];             // bank = (8*(j2+i)+w2)&31: 2-way max
            bestv = bestv > v ? bestv : v;
        }
        atomicMax(&best[g * 256 + w2 * 32 + j2], bestv);
    }
}

// ---------------- kernel 3: one-hot output from fused best[] -------------------
__global__ __launch_bounds__(256) void knn_out(const uint32_t* __restrict__ best,
                                               const int* __restrict__ meanings,
                                               float* __restrict__ out) {
    int q = blockIdx.x * 256 + threadIdx.x;
    if (q >= NQ) return;
    uint32_t b = best[q];
    int idx = 0x1FFFF - (int)(b & 0x1FFFFu);
    float* o = out + (size_t)q * 50;
    #pragma unroll
    for (int tt = 0; tt < 5; ++tt) {
        int mv = meanings[(size_t)idx * 5 + tt];
        #pragma unroll
        for (int mm = 0; mm < 10; ++mm) o[tt * 10 + mm] = (mm == mv) ? 1.0f : 0.0f;
    }
}

extern "C" void kernel_launch(void* const* d_in, const int* in_sizes, int n_in,
                              void* d_out, int out_size, void* d_ws, size_t ws_size,
                              hipStream_t stream) {
    const int*   utts     = (const int*)d_in[0];     // [16, 2048]
    const float* support  = (const float*)d_in[1];   // [100000, 512]
    const int*   meanings = (const int*)d_in[2];     // [100000, 5]
    float* out = (float*)d_out;                      // [2048, 5, 10]

    uint8_t*  tok  = (uint8_t*)d_ws;                                   // 1.6 MB
    uint32_t* best = (uint32_t*)((char*)d_ws + (size_t)S_ROWS * 16);   // 8 KB

    knn_decode<<<(S_ROWS + 3) / 4, 256, 0, stream>>>(support, tok, best);
    knn_score<<<GROUPS * CHUNKS, 256, 0, stream>>>(utts, tok, best);
    knn_out<<<NQ / 256, 256, 0, stream>>>(best, meanings, out);
}